// Round 10
// baseline (75.513 us; speedup 1.0000x reference)
//
#include <hip/hip_runtime.h>

#define CLS 64
#define DIM 256
#define NB  256          // main blocks (1/CU); NB*WIN covers N per sweep
#define WIN 1024         // rows per block window
#define MT  1024         // main threads (16 waves)
#define WPB 16           // waves per block
#define CPW 4            // classes per wave
#define SC  64           // rows per super-chunk (= lanes, one label per lane)
#define P2  4            // reduce1 parts per class

typedef float f32x4 __attribute__((ext_vector_type(4)));

// ---- wave64 sum via DPP (VALU pipe); result uniform across all lanes ----
__device__ __forceinline__ float wave_sum64(float f) {
    int t;
    t = __builtin_amdgcn_update_dpp(0, __float_as_int(f), 0x111, 0xf, 0xf, false); f += __int_as_float(t); // row_shr:1
    t = __builtin_amdgcn_update_dpp(0, __float_as_int(f), 0x112, 0xf, 0xf, false); f += __int_as_float(t); // row_shr:2
    t = __builtin_amdgcn_update_dpp(0, __float_as_int(f), 0x114, 0xf, 0xe, false); f += __int_as_float(t); // row_shr:4
    t = __builtin_amdgcn_update_dpp(0, __float_as_int(f), 0x118, 0xf, 0xc, false); f += __int_as_float(t); // row_shr:8
    t = __builtin_amdgcn_update_dpp(0, __float_as_int(f), 0x142, 0xa, 0xf, false); f += __int_as_float(t); // row_bcast:15
    t = __builtin_amdgcn_update_dpp(0, __float_as_int(f), 0x143, 0xc, 0xf, false); f += __int_as_float(t); // row_bcast:31
    return __int_as_float(__builtin_amdgcn_readlane(__float_as_int(f), 63));
}

// ---- main: balanced sequential stage -> LDS -> ballot-routed register accumulate ----
__global__ __launch_bounds__(MT) void k_main(
    const float* __restrict__ emb, const int* __restrict__ labels, int N,
    float* __restrict__ partials,   // [CLS][NB][DIM]
    float* __restrict__ cnts)       // [CLS][NB]
{
    __shared__ float buf[2][SC][DIM];          // 128 KB double-buffered normalized rows

    const int tid  = threadIdx.x;
    const int w    = tid >> 6;                 // wave: loads rows 4w..4w+3; owns classes 4w..4w+3
    const int lane = tid & 63;                 // lane l owns dims [4l, 4l+4)
    const int b    = blockIdx.x;

    f32x4 a0 = {0,0,0,0}, a1 = {0,0,0,0}, a2 = {0,0,0,0}, a3 = {0,0,0,0};
    float c0 = 0.f, c1 = 0.f, c2 = 0.f, c3 = 0.f;

    for (long long wbase = (long long)b * WIN; wbase < N; wbase += (long long)NB * WIN) {
        const int wrows = (int)min((long long)WIN, (long long)N - wbase);
        const int nsc   = (wrows + SC - 1) / SC;

        // prologue: stage chunk 0 into buf[0] (load -> normalize -> LDS)
        {
            const long long rb = wbase + 4 * w;
            #pragma unroll
            for (int i = 0; i < 4; ++i) {
                f32x4 v = {0,0,0,0};
                if (rb + i < N)
                    v = *(reinterpret_cast<const f32x4*>(emb + (size_t)(rb + i) * DIM) + lane);
                const float ss  = wave_sum64(v.x*v.x + v.y*v.y + v.z*v.z + v.w*v.w);
                const float inv = 1.0f / fmaxf(sqrtf(ss), 1e-12f);
                f32x4 t; t.x = v.x*inv; t.y = v.y*inv; t.z = v.z*inv; t.w = v.w*inv;
                *reinterpret_cast<f32x4*>(&buf[0][4*w + i][4*lane]) = t;
            }
        }
        __syncthreads();

        for (int s = 0; s < nsc; ++s) {
            const int  cur = s & 1;
            const bool hn  = (s + 1 < nsc);

            // 1) issue next chunk's 4 contiguous row-loads (4 KB/wave, 64 KB/block sequential)
            f32x4 r0 = {0,0,0,0}, r1 = {0,0,0,0}, r2 = {0,0,0,0}, r3 = {0,0,0,0};
            const long long rb = wbase + (long long)(s + 1) * SC + 4 * w;
            if (hn) {
                if (rb + 0 < N) r0 = *(reinterpret_cast<const f32x4*>(emb + (size_t)(rb + 0) * DIM) + lane);
                if (rb + 1 < N) r1 = *(reinterpret_cast<const f32x4*>(emb + (size_t)(rb + 1) * DIM) + lane);
                if (rb + 2 < N) r2 = *(reinterpret_cast<const f32x4*>(emb + (size_t)(rb + 2) * DIM) + lane);
                if (rb + 3 < N) r3 = *(reinterpret_cast<const f32x4*>(emb + (size_t)(rb + 3) * DIM) + lane);
            }

            // 2) accumulate current chunk: ballot my classes, pull rows from LDS
            const long long cb = wbase + (long long)s * SC;
            const int lab = (cb + lane < N) ? labels[cb + lane] : -1;
            unsigned long long mask = __ballot((lab >> 2) == w);
            while (mask) {
                const int r = (int)__builtin_ctzll(mask);
                mask &= mask - 1;
                const int k = __builtin_amdgcn_readlane(lab, r) & 3;   // wave-uniform
                const f32x4 v = *reinterpret_cast<const f32x4*>(&buf[cur][r][4*lane]);
                if      (k == 0) { a0 += v; c0 += 1.f; }
                else if (k == 1) { a1 += v; c1 += 1.f; }
                else if (k == 2) { a2 += v; c2 += 1.f; }
                else             { a3 += v; c3 += 1.f; }
            }

            // 3) normalize + stage next chunk into the other buffer
            if (hn) {
                const float s0 = wave_sum64(r0.x*r0.x + r0.y*r0.y + r0.z*r0.z + r0.w*r0.w);
                const float s1 = wave_sum64(r1.x*r1.x + r1.y*r1.y + r1.z*r1.z + r1.w*r1.w);
                const float s2 = wave_sum64(r2.x*r2.x + r2.y*r2.y + r2.z*r2.z + r2.w*r2.w);
                const float s3 = wave_sum64(r3.x*r3.x + r3.y*r3.y + r3.z*r3.z + r3.w*r3.w);
                const float i0 = 1.0f / fmaxf(sqrtf(s0), 1e-12f);
                const float i1 = 1.0f / fmaxf(sqrtf(s1), 1e-12f);
                const float i2 = 1.0f / fmaxf(sqrtf(s2), 1e-12f);
                const float i3 = 1.0f / fmaxf(sqrtf(s3), 1e-12f);
                f32x4 t;
                t.x = r0.x*i0; t.y = r0.y*i0; t.z = r0.z*i0; t.w = r0.w*i0;
                *reinterpret_cast<f32x4*>(&buf[cur ^ 1][4*w + 0][4*lane]) = t;
                t.x = r1.x*i1; t.y = r1.y*i1; t.z = r1.z*i1; t.w = r1.w*i1;
                *reinterpret_cast<f32x4*>(&buf[cur ^ 1][4*w + 1][4*lane]) = t;
                t.x = r2.x*i2; t.y = r2.y*i2; t.z = r2.z*i2; t.w = r2.w*i2;
                *reinterpret_cast<f32x4*>(&buf[cur ^ 1][4*w + 2][4*lane]) = t;
                t.x = r3.x*i3; t.y = r3.y*i3; t.z = r3.z*i3; t.w = r3.w*i3;
                *reinterpret_cast<f32x4*>(&buf[cur ^ 1][4*w + 3][4*lane]) = t;
            }
            __syncthreads();
        }
    }

    // epilogue: coalesced 1 KB per-class stores + counts
    *reinterpret_cast<f32x4*>(partials + ((size_t)(w*CPW + 0) * NB + b) * DIM + 4*lane) = a0;
    *reinterpret_cast<f32x4*>(partials + ((size_t)(w*CPW + 1) * NB + b) * DIM + 4*lane) = a1;
    *reinterpret_cast<f32x4*>(partials + ((size_t)(w*CPW + 2) * NB + b) * DIM + 4*lane) = a2;
    *reinterpret_cast<f32x4*>(partials + ((size_t)(w*CPW + 3) * NB + b) * DIM + 4*lane) = a3;
    if (lane == 0) {
        cnts[(size_t)(w*CPW + 0) * NB + b] = c0;
        cnts[(size_t)(w*CPW + 1) * NB + b] = c1;
        cnts[(size_t)(w*CPW + 2) * NB + b] = c2;
        cnts[(size_t)(w*CPW + 3) * NB + b] = c3;
    }
}

// ---- reduce1: fold the NB block-partials to P2 chunks per class (coalesced) ----
__global__ __launch_bounds__(256) void k_reduce1(
    const float* __restrict__ partials, float* __restrict__ red1)
{
    const int c = blockIdx.x >> 2;             // / P2
    const int p = blockIdx.x & (P2 - 1);
    const int d = threadIdx.x;                 // 256 threads = one dim each
    const float* src = partials + ((size_t)c * NB + p * (NB / P2)) * DIM + d;
    float s = 0.f;
    #pragma unroll 8
    for (int bb = 0; bb < NB / P2; ++bb) s += src[(size_t)bb * DIM];
    red1[((size_t)c * P2 + p) * DIM + d] = s;
}

// ---- per-class loss ----
__global__ __launch_bounds__(256) void k_classloss(
    const float* __restrict__ red1, const float* __restrict__ cnts,
    float* __restrict__ closs, float* __restrict__ cvalid)
{
    const int c = blockIdx.x;   // 64 blocks
    const int d = threadIdx.x;  // 256 threads
    float s = 0.f;
    #pragma unroll
    for (int p = 0; p < P2; ++p) s += red1[((size_t)c * P2 + p) * DIM + d];
    const float w2 = wave_sum64(s * s);
    const float cw = wave_sum64(cnts[(size_t)c * NB + d]);   // NB==256 block-counts
    __shared__ float reds[4], redc[4];
    if ((d & 63) == 0) { reds[d >> 6] = w2; redc[d >> 6] = cw; }
    __syncthreads();
    if (d == 0) {
        float s2   = reds[0] + reds[1] + reds[2] + reds[3];  // ||sums_c||^2
        float cnt  = redc[0] + redc[1] + redc[2] + redc[3];
        float invc = 1.0f / fmaxf(cnt, 1.0f);
        float cn   = sqrtf(s2) * invc;                       // ||center_raw||
        float dot  = s2 * invc / fmaxf(cn, 1e-12f);          // sum over class of sim
        float pcs  = cnt - dot;                              // sum over class of (1 - sim)
        bool valid = cnt > 1.0f;
        closs[c]  = valid ? pcs * invc : 0.0f;
        cvalid[c] = valid ? 1.0f : 0.0f;
    }
}

// ---- final scalar ----
__global__ void k_final(const float* __restrict__ closs, const float* __restrict__ cvalid,
                        const int* __restrict__ epoch, float* __restrict__ out)
{
    const int t = threadIdx.x;  // 64
    const float sl = wave_sum64(closs[t]);
    const float nv = wave_sum64(cvalid[t]);
    if (t == 0) {
        float res = (nv > 0.0f) ? (sl / fmaxf(nv, 1.0f)) : 0.0f;
        if (epoch[0] < 1) res = 0.0f;   // START guard
        out[0] = res;
    }
}

extern "C" void kernel_launch(void* const* d_in, const int* in_sizes, int n_in,
                              void* d_out, int out_size, void* d_ws, size_t ws_size,
                              hipStream_t stream)
{
    const float* emb    = (const float*)d_in[0];
    const int*   labels = (const int*)d_in[1];
    const int*   epoch  = (const int*)d_in[2];
    float*       out    = (float*)d_out;
    const int N = in_sizes[0] / DIM;

    // workspace carve-up (all regions fully written before read, every call)
    char* ws = (char*)d_ws;
    size_t off = 0;
    auto carve = [&](size_t bytes) { size_t o = off; off = (off + bytes + 255) & ~(size_t)255; return o; };
    float* partials = (float*)(ws + carve((size_t)CLS * NB * DIM * sizeof(float)));  // 16 MB
    float* cnts     = (float*)(ws + carve((size_t)CLS * NB * sizeof(float)));        // 64 KB
    float* red1     = (float*)(ws + carve((size_t)CLS * P2 * DIM * sizeof(float)));  // 256 KB
    float* closs    = (float*)(ws + carve((size_t)CLS * sizeof(float)));
    float* cvalid   = (float*)(ws + carve((size_t)CLS * sizeof(float)));
    (void)ws_size;  // ~16.4 MB needed; harness provides ~1 GiB (observed via poison fill)

    k_main     <<<NB,       MT,  0, stream>>>(emb, labels, N, partials, cnts);
    k_reduce1  <<<CLS * P2, 256, 0, stream>>>(partials, red1);
    k_classloss<<<CLS,      256, 0, stream>>>(red1, cnts, closs, cvalid);
    k_final    <<<1,        64,  0, stream>>>(closs, cvalid, epoch, out);
}